// Round 3
// baseline (76.866 us; speedup 1.0000x reference)
//
#include <hip/hip_runtime.h>
#include <stdint.h>

typedef __bf16 bf16_t;
typedef __bf16 bf16x8 __attribute__((ext_vector_type(8)));
typedef float f32x4 __attribute__((ext_vector_type(4)));
typedef unsigned short ushort8 __attribute__((ext_vector_type(8)));

#define M_DIM 16384
#define N_DIM 1024
#define K_DIM 1024
#define BM 256
#define BN 256
#define BK 32
#define NT (K_DIM / BK)          // 32 K-tiles
#define AB_ELEMS (BM * BK)       // 8192 elems (16 KB) per operand per buffer
#define BUF_ELEMS (2 * AB_ELEMS) // A then B
// 4 buffers * 32 KB = 128 KB LDS

// ------- W: binarize (exact reference semantics) + transpose to [N][K] -------
__global__ void bin_transpose_w(const float* __restrict__ W,
                                unsigned short* __restrict__ WbT) {
    __shared__ unsigned short t[64][68];
    int tj = blockIdx.x;                   // n tile
    int ti = blockIdx.y;                   // k tile
    int tid = threadIdx.x;
    int c4 = (tid & 15) * 4;
    int r0 = tid >> 4;
#pragma unroll
    for (int p = 0; p < 4; ++p) {
        int r = r0 + p * 16;
        float4 v = *(const float4*)(W + (size_t)(ti * 64 + r) * N_DIM + tj * 64 + c4);
        // reference: +1 iff (w+1)/2 > 0.5 (round-half-even at exactly 0.5 -> -1)
        t[r][c4 + 0] = ((v.x + 1.0f) * 0.5f > 0.5f) ? 0x3F80 : 0xBF80;
        t[r][c4 + 1] = ((v.y + 1.0f) * 0.5f > 0.5f) ? 0x3F80 : 0xBF80;
        t[r][c4 + 2] = ((v.z + 1.0f) * 0.5f > 0.5f) ? 0x3F80 : 0xBF80;
        t[r][c4 + 3] = ((v.w + 1.0f) * 0.5f > 0.5f) ? 0x3F80 : 0xBF80;
    }
    __syncthreads();
#pragma unroll
    for (int p = 0; p < 4; ++p) {
        int rn = r0 + p * 16;
        ushort4 o;
        o.x = t[c4 + 0][rn];
        o.y = t[c4 + 1][rn];
        o.z = t[c4 + 2][rn];
        o.w = t[c4 + 3][rn];
        *(ushort4*)(WbT + (size_t)(tj * 64 + rn) * K_DIM + ti * 64 + c4) = o;
    }
}

// ---------------- fused cvt + pipelined bf16 GEMM ----------------
__device__ __forceinline__ void gload16(const bf16_t* g, const bf16_t* l) {
    __builtin_amdgcn_global_load_lds(
        (const __attribute__((address_space(1))) void*)(g),
        (__attribute__((address_space(3))) void*)(l),
        16, 0, 0);
}

__device__ __forceinline__ bf16x8 cvt8(float4 a, float4 b) {
    union { ushort8 u; bf16x8 h; } r;
    float v[8] = {a.x, a.y, a.z, a.w, b.x, b.y, b.z, b.w};
#pragma unroll
    for (int j = 0; j < 8; ++j) {
        uint32_t u = __builtin_bit_cast(uint32_t, v[j]);
        u = u + 0x7FFFu + ((u >> 16) & 1u);   // round-to-nearest-even
        r.u[j] = (unsigned short)(u >> 16);
    }
    return r.h;
}

__global__ __launch_bounds__(512, 2) void bgemm(const float* __restrict__ X,
                                                const bf16_t* __restrict__ Bt,
                                                const float* __restrict__ bias,
                                                float* __restrict__ C) {
    __shared__ __align__(16) bf16_t lds[4 * BUF_ELEMS];   // 128 KB

    const int nwg = (M_DIM / BM) * (N_DIM / BN);   // 256, %8==0
    int bid = blockIdx.x;
    int swz = (bid & 7) * (nwg >> 3) + (bid >> 3); // XCD-aware, bijective
    int tile_m = swz % (M_DIM / BM);
    int tile_n = swz / (M_DIM / BM);
    int bm0 = tile_m * BM;
    int bn0 = tile_n * BN;

    int tid = threadIdx.x;
    int w = tid >> 6, l = tid & 63;    // 8 waves: 2(M) x 4(N)
    int wr = w >> 2, wc = w & 3;       // per-wave 128x64 output
    int lr = l & 15, lk = l >> 4;
    int rdchunk = (lk ^ ((lr >> 1) & 3)) * 8;       // T2 swizzled read chunk
    int bsrc = ((l & 3) ^ ((l >> 3) & 3)) * 8;      // inverse-swz B source chunk
    int ar = tid >> 1, ah = tid & 1;                // A-stage row / half
    int as = (ar >> 1) & 3;                         // A write swizzle selector

    // B stage: gload_lds, linear LDS dest (wave base + lane*16), pre-swizzled src
    auto stageB = [&](int t, int boff) {
#pragma unroll
        for (int i = 0; i < 2; ++i) {
            int row = i * 128 + w * 16 + (l >> 2);
            gload16(Bt + (size_t)(bn0 + row) * K_DIM + t * BK + bsrc,
                    lds + boff + AB_ELEMS + i * 4096 + w * 512);
        }
    };
    // A stage: f32 -> reg (issue early), cvt+ds_write one tile later (T14)
    auto loadA = [&](int t, float4& a0, float4& a1, float4& a2, float4& a3) {
        const float4* s = (const float4*)(X + (size_t)(bm0 + ar) * K_DIM + t * BK + ah * 16);
        a0 = s[0]; a1 = s[1]; a2 = s[2]; a3 = s[3];
    };
    auto writeA = [&](int boff, float4 a0, float4 a1, float4 a2, float4 a3) {
        bf16x8 w0 = cvt8(a0, a1), w1 = cvt8(a2, a3);
        *(bf16x8*)(lds + boff + ar * 32 + (((ah * 2) ^ as) * 8)) = w0;
        *(bf16x8*)(lds + boff + ar * 32 + (((ah * 2 + 1) ^ as) * 8)) = w1;
    };

    f32x4 acc[8][4];
#pragma unroll
    for (int m = 0; m < 8; ++m)
#pragma unroll
        for (int n = 0; n < 4; ++n)
            acc[m][n] = (f32x4)(0.0f);

    // ---- prologue: stage tiles 0,1,2 (A via reg, B via gload_lds) ----
    float4 p0, p1, p2, p3, q0, q1, q2, q3, oa0, oa1, oa2, oa3;
    loadA(0, p0, p1, p2, p3);   stageB(0, 0);
    loadA(1, q0, q1, q2, q3);   stageB(1, BUF_ELEMS);
    loadA(2, oa0, oa1, oa2, oa3); stageB(2, 2 * BUF_ELEMS);
    asm volatile("s_waitcnt vmcnt(12)" ::: "memory");   // retire A0,B0
    writeA(0, p0, p1, p2, p3);
    asm volatile("s_waitcnt vmcnt(6)" ::: "memory");    // retire A1,B1
    writeA(BUF_ELEMS, q0, q1, q2, q3);
    asm volatile("s_waitcnt lgkmcnt(0)" ::: "memory");
    __builtin_amdgcn_sched_barrier(0);
    __builtin_amdgcn_s_barrier();

    for (int t = 0; t < NT; ++t) {
        const bf16_t* Ab = lds + (t & 3) * BUF_ELEMS;
        const bf16_t* Bb = Ab + AB_ELEMS;

        // ---- phase 1: read B all + A half 0; stage tile t+3; write A(t+2) ----
        bf16x8 bfr[4], afr[4];
#pragma unroll
        for (int n = 0; n < 4; ++n)
            bfr[n] = *(const bf16x8*)(Bb + (wc * 64 + n * 16 + lr) * 32 + rdchunk);
#pragma unroll
        for (int m = 0; m < 4; ++m)
            afr[m] = *(const bf16x8*)(Ab + (wr * 128 + m * 16 + lr) * 32 + rdchunk);

        float4 na0, na1, na2, na3;
        if (t + 3 < NT) {
            loadA(t + 3, na0, na1, na2, na3);          // 4 dwordx4 (oldest of new)
            stageB(t + 3, ((t + 3) & 3) * BUF_ELEMS);  // 2 gload_lds
        }
        // counted waits: retire exactly B(t+1) [buffer residency] + A(t+2) [regs]
        if (t <= NT - 4)      asm volatile("s_waitcnt vmcnt(8)" ::: "memory");
        else if (t == NT - 3) asm volatile("s_waitcnt vmcnt(2)" ::: "memory");
        else if (t == NT - 2) asm volatile("s_waitcnt vmcnt(0)" ::: "memory");
        if (t + 2 < NT)
            writeA(((t + 2) & 3) * BUF_ELEMS, oa0, oa1, oa2, oa3);
        if (t + 3 < NT) { oa0 = na0; oa1 = na1; oa2 = na2; oa3 = na3; }

        __builtin_amdgcn_s_barrier();
        asm volatile("s_waitcnt lgkmcnt(0)" ::: "memory");
        __builtin_amdgcn_sched_barrier(0);
        __builtin_amdgcn_s_setprio(1);
#pragma unroll
        for (int m = 0; m < 4; ++m)
#pragma unroll
            for (int n = 0; n < 4; ++n)
                acc[m][n] = __builtin_amdgcn_mfma_f32_16x16x32_bf16(
                    afr[m], bfr[n], acc[m][n], 0, 0, 0);
        __builtin_amdgcn_s_setprio(0);
        __builtin_amdgcn_s_barrier();

        // ---- phase 2: read A half 1; B frags reused from registers ----
#pragma unroll
        for (int m = 0; m < 4; ++m)
            afr[m] = *(const bf16x8*)(Ab + (wr * 128 + (m + 4) * 16 + lr) * 32 + rdchunk);
        __builtin_amdgcn_s_barrier();
        asm volatile("s_waitcnt lgkmcnt(0)" ::: "memory");
        __builtin_amdgcn_sched_barrier(0);
        __builtin_amdgcn_s_setprio(1);
#pragma unroll
        for (int m = 0; m < 4; ++m)
#pragma unroll
            for (int n = 0; n < 4; ++n)
                acc[m + 4][n] = __builtin_amdgcn_mfma_f32_16x16x32_bf16(
                    afr[m], bfr[n], acc[m + 4][n], 0, 0, 0);
        __builtin_amdgcn_s_setprio(0);
        __builtin_amdgcn_s_barrier();
    }

    // ---- epilogue: C/D layout col = lane&15, row = (lane>>4)*4 + reg ----
#pragma unroll
    for (int n = 0; n < 4; ++n) {
        int col = bn0 + wc * 64 + n * 16 + lr;
        float bv = bias[col];
#pragma unroll
        for (int m = 0; m < 8; ++m) {
            int row0 = bm0 + wr * 128 + m * 16 + lk * 4;
#pragma unroll
            for (int j = 0; j < 4; ++j)
                C[(size_t)(row0 + j) * N_DIM + col] = acc[m][n][j] + bv;
        }
    }
}

// ---------------- fallback (only if workspace too small) ----------------
__global__ void naive_bin_dense(const float* __restrict__ x,
                                const float* __restrict__ W,
                                const float* __restrict__ b,
                                float* __restrict__ out) {
    int col = blockIdx.x * 256 + threadIdx.x;
    int row = blockIdx.y;
    float acc = 0.0f;
    for (int k = 0; k < K_DIM; ++k) {
        float s = ((W[(size_t)k * N_DIM + col] + 1.0f) * 0.5f > 0.5f) ? 1.0f : -1.0f;
        acc += x[(size_t)row * K_DIM + k] * s;
    }
    out[(size_t)row * N_DIM + col] = acc + b[col];
}

extern "C" void kernel_launch(void* const* d_in, const int* in_sizes, int n_in,
                              void* d_out, int out_size, void* d_ws, size_t ws_size,
                              hipStream_t stream) {
    const float* x = (const float*)d_in[0];
    const float* W = (const float*)d_in[1];
    const float* b = (const float*)d_in[2];
    float* out = (float*)d_out;

    size_t wb_bytes = (size_t)K_DIM * N_DIM * sizeof(unsigned short);

    if (ws_size >= wb_bytes) {
        unsigned short* wbt = (unsigned short*)d_ws;
        hipLaunchKernelGGL(bin_transpose_w, dim3(N_DIM / 64, K_DIM / 64), dim3(256),
                           0, stream, W, wbt);
        hipLaunchKernelGGL(bgemm, dim3((M_DIM / BM) * (N_DIM / BN)), dim3(512), 0, stream,
                           x, (const bf16_t*)wbt, b, out);
    } else {
        hipLaunchKernelGGL(naive_bin_dense, dim3(N_DIM / 256, M_DIM), dim3(256),
                           0, stream, x, W, b, out);
    }
}

// Round 4
// 62.797 us; speedup vs baseline: 1.2240x; 1.2240x over previous
//
#include <hip/hip_runtime.h>
#include <stdint.h>

typedef __bf16 bf16_t;
typedef __bf16 bf16x8 __attribute__((ext_vector_type(8)));
typedef float f32x4 __attribute__((ext_vector_type(4)));
typedef unsigned short ushort8 __attribute__((ext_vector_type(8)));

#define M_DIM 16384
#define N_DIM 1024
#define K_DIM 1024
#define BM 256
#define BN 256
#define BK 64
#define NT (K_DIM / BK)            // 16 K-tiles
#define AB_ELEMS (BM * BK)         // 16384 elems = 32 KB per operand
#define BUF_ELEMS (2 * AB_ELEMS)   // 64 KB per buffer; 2 buffers = 128 KB

// ---------------- x: f32 -> bf16 (RNE), vectorized ----------------
__global__ void cvt_x_bf16(const float* __restrict__ x,
                           unsigned short* __restrict__ xb, int n8) {
    int i = blockIdx.x * blockDim.x + threadIdx.x;
    int stride = gridDim.x * blockDim.x;
    for (; i < n8; i += stride) {
        const float4* p = (const float4*)(x + (size_t)i * 8);
        float4 v0 = p[0], v1 = p[1];
        float vv[8] = {v0.x, v0.y, v0.z, v0.w, v1.x, v1.y, v1.z, v1.w};
        ushort8 o;
#pragma unroll
        for (int j = 0; j < 8; ++j) {
            uint32_t u = __builtin_bit_cast(uint32_t, vv[j]);
            u = u + 0x7FFFu + ((u >> 16) & 1u);   // round-to-nearest-even
            o[j] = (unsigned short)(u >> 16);
        }
        *(ushort8*)(xb + (size_t)i * 8) = o;
    }
}

// ------- W: binarize (exact reference semantics) + transpose to [N][K] -------
__global__ void bin_transpose_w(const float* __restrict__ W,
                                unsigned short* __restrict__ WbT) {
    __shared__ unsigned short t[64][68];
    int tj = blockIdx.x;                   // n tile
    int ti = blockIdx.y;                   // k tile
    int tid = threadIdx.x;
    int c4 = (tid & 15) * 4;
    int r0 = tid >> 4;
#pragma unroll
    for (int p = 0; p < 4; ++p) {
        int r = r0 + p * 16;
        float4 v = *(const float4*)(W + (size_t)(ti * 64 + r) * N_DIM + tj * 64 + c4);
        // reference: +1 iff (w+1)/2 > 0.5 (round-half-even at exactly 0.5 -> -1)
        t[r][c4 + 0] = ((v.x + 1.0f) * 0.5f > 0.5f) ? 0x3F80 : 0xBF80;
        t[r][c4 + 1] = ((v.y + 1.0f) * 0.5f > 0.5f) ? 0x3F80 : 0xBF80;
        t[r][c4 + 2] = ((v.z + 1.0f) * 0.5f > 0.5f) ? 0x3F80 : 0xBF80;
        t[r][c4 + 3] = ((v.w + 1.0f) * 0.5f > 0.5f) ? 0x3F80 : 0xBF80;
    }
    __syncthreads();
#pragma unroll
    for (int p = 0; p < 4; ++p) {
        int rn = r0 + p * 16;
        ushort4 o;
        o.x = t[c4 + 0][rn];
        o.y = t[c4 + 1][rn];
        o.z = t[c4 + 2][rn];
        o.w = t[c4 + 3][rn];
        *(ushort4*)(WbT + (size_t)(tj * 64 + rn) * K_DIM + ti * 64 + c4) = o;
    }
}

// ---------------- 8-phase-template bf16 GEMM: C = A * Bt^T + bias ----------------
__device__ __forceinline__ void gload16(const bf16_t* g, const bf16_t* l) {
    __builtin_amdgcn_global_load_lds(
        (const __attribute__((address_space(1))) void*)(g),
        (__attribute__((address_space(3))) void*)(l),
        16, 0, 0);
}

// one phase: 4 A ds_reads + 2 stage issues -> barrier -> 16 MFMA
#define PHASE_BODY(P, S0, S1)                                                   \
    {                                                                           \
        bf16x8 afr[2][2];                                                       \
        _Pragma("unroll") for (int i = 0; i < 2; ++i)                           \
            _Pragma("unroll") for (int k = 0; k < 2; ++k)                       \
                afr[i][k] = *(const bf16x8*)(Ab + (wr * 128 + ((P)*2 + i) * 16 + lr) * BK \
                                             + (((k * 4 + lk) ^ l7) * 8));      \
        S0; S1;                                                                 \
        __builtin_amdgcn_s_barrier();                                           \
        asm volatile("s_waitcnt lgkmcnt(0)" ::: "memory");                      \
        __builtin_amdgcn_sched_barrier(0);                                      \
        __builtin_amdgcn_s_setprio(1);                                          \
        _Pragma("unroll") for (int i = 0; i < 2; ++i)                           \
            _Pragma("unroll") for (int n = 0; n < 4; ++n)                       \
                _Pragma("unroll") for (int k = 0; k < 2; ++k)                   \
                    acc[(P)*2 + i][n] = __builtin_amdgcn_mfma_f32_16x16x32_bf16(\
                        afr[i][k], bfr[n][k], acc[(P)*2 + i][n], 0, 0, 0);      \
        __builtin_amdgcn_s_setprio(0);                                          \
    }

__global__ __launch_bounds__(512, 2) void bgemm(const bf16_t* __restrict__ A,
                                                const bf16_t* __restrict__ Bt,
                                                const float* __restrict__ bias,
                                                float* __restrict__ C) {
    __shared__ __align__(16) bf16_t lds[2 * BUF_ELEMS];   // 128 KB

    const int nwg = (M_DIM / BM) * (N_DIM / BN);   // 256, %8==0
    int bid = blockIdx.x;
    int swz = (bid & 7) * (nwg >> 3) + (bid >> 3); // XCD-aware, bijective
    int tile_n = swz & 3;                          // consecutive swz share A panel
    int tile_m = swz >> 2;
    int bm0 = tile_m * BM;
    int bn0 = tile_n * BN;

    int tid = threadIdx.x;
    int w = tid >> 6, l = tid & 63;    // 8 waves: 2(M) x 4(N)
    int wr = w >> 2, wc = w & 3;       // per-wave 128x64 output
    int lr = l & 15, lk = l >> 4, l7 = l & 7;

    // staging: linear LDS dest (wave-uniform base + lane*16B); T2 swizzle via
    // pre-swizzled per-lane GLOBAL source chunk (both-sides rule)
    int srow8 = tid >> 3;                        // row within 64-row call
    int schunk = (tid & 7) ^ (srow8 & 7);        // inverse-swizzled source chunk
    auto stageA1 = [&](int t, int boff, int c) {
        gload16(A + (size_t)(bm0 + c * 64 + srow8) * K_DIM + t * BK + schunk * 8,
                lds + boff + c * 4096 + tid * 8);
    };
    auto stageB1 = [&](int t, int boff, int c) {
        gload16(Bt + (size_t)(bn0 + c * 64 + srow8) * K_DIM + t * BK + schunk * 8,
                lds + boff + AB_ELEMS + c * 4096 + tid * 8);
    };

    f32x4 acc[8][4];
#pragma unroll
    for (int m = 0; m < 8; ++m)
#pragma unroll
        for (int n = 0; n < 4; ++n)
            acc[m][n] = (f32x4)(0.0f);

    // ---- prologue: stage tile 0 (8 calls), drain, barrier ----
#pragma unroll
    for (int c = 0; c < 4; ++c) stageA1(0, 0, c);
#pragma unroll
    for (int c = 0; c < 4; ++c) stageB1(0, 0, c);
    asm volatile("s_waitcnt vmcnt(0)" ::: "memory");
    __builtin_amdgcn_s_barrier();

    for (int t = 0; t < NT; ++t) {
        const bf16_t* Ab = lds + (t & 1) * BUF_ELEMS;
        const bf16_t* Bb = Ab + AB_ELEMS;
        int sb = ((t + 1) & 1) * BUF_ELEMS;
        bool pf = (t + 1) < NT;

        // B frags: loaded once in phase 0, register-resident for all 4 phases
        bf16x8 bfr[4][2];
#pragma unroll
        for (int n = 0; n < 4; ++n)
#pragma unroll
            for (int k = 0; k < 2; ++k)
                bfr[n][k] = *(const bf16x8*)(Bb + (wc * 64 + n * 16 + lr) * BK
                                             + (((k * 4 + lk) ^ l7) * 8));

        PHASE_BODY(0, if (pf) stageA1(t + 1, sb, 0), if (pf) stageA1(t + 1, sb, 1));
        __builtin_amdgcn_s_barrier();
        PHASE_BODY(1, if (pf) stageA1(t + 1, sb, 2), if (pf) stageA1(t + 1, sb, 3));
        __builtin_amdgcn_s_barrier();
        PHASE_BODY(2, if (pf) stageB1(t + 1, sb, 0), if (pf) stageB1(t + 1, sb, 1));
        __builtin_amdgcn_s_barrier();
        PHASE_BODY(3, if (pf) stageB1(t + 1, sb, 2), if (pf) stageB1(t + 1, sb, 3));

        // ---- tile boundary: all of tile t+1 issued phases ago; drain + rendezvous
        if (pf) {
            asm volatile("s_waitcnt vmcnt(0)" ::: "memory");
            __builtin_amdgcn_s_barrier();
        }
    }

    // ---- epilogue: C/D layout col = lane&15, row = (lane>>4)*4 + reg ----
#pragma unroll
    for (int n = 0; n < 4; ++n) {
        int col = bn0 + wc * 64 + n * 16 + lr;
        float bv = bias[col];
#pragma unroll
        for (int m = 0; m < 8; ++m) {
            int row0 = bm0 + wr * 128 + m * 16 + lk * 4;
#pragma unroll
            for (int j = 0; j < 4; ++j)
                C[(size_t)(row0 + j) * N_DIM + col] = acc[m][n][j] + bv;
        }
    }
}

// ---------------- fallback (only if workspace too small) ----------------
__global__ void naive_bin_dense(const float* __restrict__ x,
                                const float* __restrict__ W,
                                const float* __restrict__ b,
                                float* __restrict__ out) {
    int col = blockIdx.x * 256 + threadIdx.x;
    int row = blockIdx.y;
    float acc = 0.0f;
    for (int k = 0; k < K_DIM; ++k) {
        float s = ((W[(size_t)k * N_DIM + col] + 1.0f) * 0.5f > 0.5f) ? 1.0f : -1.0f;
        acc += x[(size_t)row * K_DIM + k] * s;
    }
    out[(size_t)row * N_DIM + col] = acc + b[col];
}

extern "C" void kernel_launch(void* const* d_in, const int* in_sizes, int n_in,
                              void* d_out, int out_size, void* d_ws, size_t ws_size,
                              hipStream_t stream) {
    const float* x = (const float*)d_in[0];
    const float* W = (const float*)d_in[1];
    const float* b = (const float*)d_in[2];
    float* out = (float*)d_out;

    size_t xb_bytes = (size_t)M_DIM * K_DIM * sizeof(unsigned short);
    size_t wb_bytes = (size_t)K_DIM * N_DIM * sizeof(unsigned short);

    if (ws_size >= xb_bytes + wb_bytes) {
        unsigned short* xb = (unsigned short*)d_ws;
        unsigned short* wbt = (unsigned short*)((char*)d_ws + xb_bytes);
        hipLaunchKernelGGL(bin_transpose_w, dim3(N_DIM / 64, K_DIM / 64), dim3(256),
                           0, stream, W, wbt);
        hipLaunchKernelGGL(cvt_x_bf16, dim3(2048), dim3(256), 0, stream,
                           x, xb, (M_DIM * K_DIM) / 8);
        hipLaunchKernelGGL(bgemm, dim3((M_DIM / BM) * (N_DIM / BN)), dim3(512), 0, stream,
                           (const bf16_t*)xb, (const bf16_t*)wbt, b, out);
    } else {
        hipLaunchKernelGGL(naive_bin_dense, dim3(N_DIM / 256, M_DIM), dim3(256),
                           0, stream, x, W, b, out);
    }
}